// Round 2
// baseline (259.783 us; speedup 1.0000x reference)
//
#include <hip/hip_runtime.h>
#include <cstdint>
#include <cstddef>

typedef unsigned short u16;
typedef __bf16 bf16x8 __attribute__((ext_vector_type(8)));
typedef float f32x4 __attribute__((ext_vector_type(4)));
typedef unsigned int u32x4 __attribute__((ext_vector_type(4)));

#define SCALE_QK 0.17677669529663687f  // 32^-0.5

__device__ __forceinline__ u16 f2bf(float f){ return __builtin_bit_cast(u16, (__bf16)f); }
__device__ __forceinline__ bf16x8 ldfrag_g(const u16* p){
  return __builtin_bit_cast(bf16x8, *reinterpret_cast<const u32x4*>(p));
}

// ---------------- K0: f32 -> bf16 convert ----------------
__global__ __launch_bounds__(256) void k_cvt(const float* __restrict__ src,
                                             u16* __restrict__ dst, int n4){
  int stride = gridDim.x * blockDim.x;
  for (int idx = blockIdx.x*blockDim.x + threadIdx.x; idx < n4; idx += stride){
    float4 v = reinterpret_cast<const float4*>(src)[idx];
    ushort4 o;
    o.x = f2bf(v.x); o.y = f2bf(v.y); o.z = f2bf(v.z); o.w = f2bf(v.w);
    reinterpret_cast<ushort4*>(dst)[idx] = o;
  }
}

// ---------------- K1: pair bias + mask -> bias[h][n][m] f32 ----------------
__global__ __launch_bounds__(256) void k_pair_bias(const float* __restrict__ pair,
        const int* __restrict__ mask, const float* __restrict__ Wpb,
        const float* __restrict__ bpb, float* __restrict__ bias){
  __shared__ float wsm[8][128];
  __shared__ float bsm[8];
  int tid = threadIdx.x;
  for (int i = tid; i < 1024; i += 256) wsm[i>>7][i&127] = Wpb[i];
  if (tid < 8) bsm[tid] = bpb[tid];
  __syncthreads();
  int g = tid>>4, l = tid&15;
  int row = blockIdx.x*16 + g;             // n*256 + m
  const float4* p = reinterpret_cast<const float4*>(pair + (size_t)row*128);
  float4 a0 = p[l];
  float4 a1 = p[l+16];
  int c0 = 4*l, c1 = 64 + 4*l;
  float acc[8];
#pragma unroll
  for (int hh=0; hh<8; hh++){
    acc[hh] = a0.x*wsm[hh][c0] + a0.y*wsm[hh][c0+1] + a0.z*wsm[hh][c0+2] + a0.w*wsm[hh][c0+3]
            + a1.x*wsm[hh][c1] + a1.y*wsm[hh][c1+1] + a1.z*wsm[hh][c1+2] + a1.w*wsm[hh][c1+3];
  }
#pragma unroll
  for (int hh=0; hh<8; hh++){
    float v = acc[hh];
    v += __shfl_xor(v,1); v += __shfl_xor(v,2); v += __shfl_xor(v,4); v += __shfl_xor(v,8);
    acc[hh] = v;
  }
  if (l == 0){
    float mb = (mask[row] == 0) ? -1e9f : 0.0f;
#pragma unroll
    for (int hh=0; hh<8; hh++)
      bias[hh*65536 + row] = acc[hh] + bsm[hh] + mb;
  }
}

// ---------------- K2: QKV GEMM (32768x768x256, bf16 MFMA) ----------------
// A = msa_bf16 [32768][256]; B = Wqkv_bf16 [768][256] (N x K); out qkv bf16 [t][h][32768][32]
__global__ __launch_bounds__(256) void k_qkv(const u16* __restrict__ A,
                                             const u16* __restrict__ B,
                                             const float* __restrict__ bq,
                                             u16* __restrict__ qkv){
  __shared__ __align__(16) u16 Al[128*64];
  __shared__ __align__(16) u16 Bl[128*64];
  const int tid = threadIdx.x;
  const int w = tid>>6, l = tid&63;
  const int wm = w>>1, wn = w&1;
  const int m0 = blockIdx.y*128, n0 = blockIdx.x*128;
  const int lr = l&15, lg = l>>4;
  f32x4 acc[4][4] = {};
  for (int kt=0; kt<4; ++kt){
    const int k0 = kt*64;
    __syncthreads();
#pragma unroll
    for (int i=0;i<4;i++){
      int flat = tid + 256*i;                 // 1024 16B-chunks
      int r = flat>>3, sl = flat&7;
      u32x4 da = *reinterpret_cast<const u32x4*>(A + (size_t)(m0+r)*256 + k0 + sl*8);
      u32x4 db = *reinterpret_cast<const u32x4*>(B + (size_t)(n0+r)*256 + k0 + sl*8);
      *reinterpret_cast<u32x4*>(&Al[r*64 + ((sl^(r&7))*8)]) = da;
      *reinterpret_cast<u32x4*>(&Bl[r*64 + ((sl^(r&7))*8)]) = db;
    }
    __syncthreads();
#pragma unroll
    for (int ks=0; ks<2; ++ks){
      bf16x8 af[4], bfr[4];
#pragma unroll
      for (int t=0;t<4;t++){
        int ra = wm*64 + t*16 + lr;
        int sa = (ks*4 + lg) ^ (ra&7);
        af[t] = __builtin_bit_cast(bf16x8, *reinterpret_cast<const u32x4*>(&Al[ra*64 + sa*8]));
        int rb = wn*64 + t*16 + lr;
        int sb = (ks*4 + lg) ^ (rb&7);
        bfr[t] = __builtin_bit_cast(bf16x8, *reinterpret_cast<const u32x4*>(&Bl[rb*64 + sb*8]));
      }
#pragma unroll
      for (int tm=0;tm<4;tm++)
#pragma unroll
        for (int tn=0;tn<4;tn++)
          acc[tm][tn] = __builtin_amdgcn_mfma_f32_16x16x32_bf16(af[tm], bfr[tn], acc[tm][tn], 0,0,0);
    }
  }
  // epilogue: +bias, scatter to [t][h][m][dh] bf16
#pragma unroll
  for (int tn=0;tn<4;tn++){
    int c = n0 + wn*64 + tn*16 + lr;       // 0..767
    int t3 = c>>8, hh = (c>>5)&7, dh = c&31;
    float bb = bq[c];
    u16* obase = qkv + (size_t)(t3*8+hh)*32768*32 + dh;
#pragma unroll
    for (int tm=0;tm<4;tm++){
#pragma unroll
      for (int rr=0;rr<4;rr++){
        int m = m0 + wm*64 + tm*16 + lg*4 + rr;
        obase[(size_t)m*32] = f2bf(acc[tm][tn][rr] + bb);
      }
    }
  }
}

// ---------------- K3: attention per (s,h) ----------------
__global__ __launch_bounds__(256) void k_attn(const u16* __restrict__ qkv,
                                              const float* __restrict__ bias,
                                              u16* __restrict__ O){
  __shared__ __align__(16) u16 vT[32*256];     // [dh][m], XOR-swizzled 16B slots
  __shared__ __align__(16) u16 P[4][64*64];    // per-wave P tile, swizzled
  const int h = blockIdx.x, s = blockIdx.y;
  const int tid = threadIdx.x;
  const int w = tid>>6, l = tid&63;
  const int lr = l&15, lg = l>>4;
  const u16* qb = qkv + ((size_t)(0*8+h)*32768 + s*256)*32;
  const u16* kb = qkv + ((size_t)(8+h)*32768 + s*256)*32;
  const u16* vb = qkv + ((size_t)(16+h)*32768 + s*256)*32;
  const float* bb = bias + h*65536;

  // stage V transposed: vT[dh][m]
#pragma unroll
  for (int i=0;i<4;i++){
    int flat4 = tid + 256*i;                 // 1024 chunks of 8 elems
    int m = flat4>>2, d0 = (flat4&3)*8;
    u32x4 d = *reinterpret_cast<const u32x4*>(vb + (size_t)m*32 + d0);
    u16 tmp[8];
    *reinterpret_cast<u32x4*>(tmp) = d;
#pragma unroll
    for (int j=0;j<8;j++){
      int dh = d0 + j;
      vT[dh*256 + (((m>>3)^(dh&7))*8) + (m&7)] = tmp[j];
    }
  }
  __syncthreads();

  bf16x8 qf[4];
#pragma unroll
  for (int tm=0;tm<4;tm++)
    qf[tm] = ldfrag_g(qb + (size_t)(64*w + tm*16 + lr)*32 + lg*8);

  f32x4 oacc[4][2] = {};
  float mrun[4][4], lrun[4][4];
#pragma unroll
  for (int tm=0;tm<4;tm++)
#pragma unroll
    for (int rr=0;rr<4;rr++){ mrun[tm][rr] = -3e38f; lrun[tm][rr] = 0.f; }

  for (int mt=0; mt<4; ++mt){
    bf16x8 kf[4];
#pragma unroll
    for (int tn=0;tn<4;tn++)
      kf[tn] = ldfrag_g(kb + (size_t)(mt*64 + tn*16 + lr)*32 + lg*8);
    f32x4 sacc[4][4] = {};
#pragma unroll
    for (int tm=0;tm<4;tm++)
#pragma unroll
      for (int tn=0;tn<4;tn++)
        sacc[tm][tn] = __builtin_amdgcn_mfma_f32_16x16x32_bf16(qf[tm], kf[tn], sacc[tm][tn], 0,0,0);
    // scale + bias(+mask)
#pragma unroll
    for (int tm=0;tm<4;tm++){
#pragma unroll
      for (int rr=0;rr<4;rr++){
        int n = 64*w + tm*16 + lg*4 + rr;
        const float* brow = bb + n*256 + mt*64;
#pragma unroll
        for (int tn=0;tn<4;tn++)
          sacc[tm][tn][rr] = sacc[tm][tn][rr]*SCALE_QK + brow[tn*16 + lr];
      }
    }
    // online softmax per row
#pragma unroll
    for (int tm=0;tm<4;tm++){
#pragma unroll
      for (int rr=0;rr<4;rr++){
        float mx = fmaxf(fmaxf(sacc[tm][0][rr], sacc[tm][1][rr]),
                         fmaxf(sacc[tm][2][rr], sacc[tm][3][rr]));
        mx = fmaxf(mx, __shfl_xor(mx,1));
        mx = fmaxf(mx, __shfl_xor(mx,2));
        mx = fmaxf(mx, __shfl_xor(mx,4));
        mx = fmaxf(mx, __shfl_xor(mx,8));
        float mo = mrun[tm][rr];
        float mn = fmaxf(mo, mx);
        float corr = __expf(mo - mn);
        mrun[tm][rr] = mn;
        float ps = 0.f;
#pragma unroll
        for (int tn=0;tn<4;tn++){
          float p = __expf(sacc[tm][tn][rr] - mn);
          sacc[tm][tn][rr] = p;
          ps += p;
        }
        ps += __shfl_xor(ps,1);
        ps += __shfl_xor(ps,2);
        ps += __shfl_xor(ps,4);
        ps += __shfl_xor(ps,8);
        lrun[tm][rr] = lrun[tm][rr]*corr + ps;
        oacc[tm][0][rr] *= corr;
        oacc[tm][1][rr] *= corr;
      }
    }
    // write P (bf16) to per-wave LDS, transposed layout for A-frags
#pragma unroll
    for (int tm=0;tm<4;tm++){
#pragma unroll
      for (int rr=0;rr<4;rr++){
        int row = tm*16 + lg*4 + rr;
        int rb = row*64;
        int sx = row&7;
#pragma unroll
        for (int tn=0;tn<4;tn++){
          int col = tn*16 + lr;
          P[w][rb + (((col>>3)^sx)*8) + (col&7)] = f2bf(sacc[tm][tn][rr]);
        }
      }
    }
    // PV
#pragma unroll
    for (int kk=0;kk<2;kk++){
      bf16x8 vf[2];
#pragma unroll
      for (int dt=0;dt<2;dt++){
        int c = dt*16 + lr;
        int slot = (mt*8 + kk*4 + lg) ^ (c&7);
        vf[dt] = __builtin_bit_cast(bf16x8, *reinterpret_cast<const u32x4*>(&vT[c*256 + slot*8]));
      }
#pragma unroll
      for (int tm=0;tm<4;tm++){
        int ra = tm*16 + lr;
        int sa = (kk*4 + lg) ^ (ra&7);
        bf16x8 pf = __builtin_bit_cast(bf16x8, *reinterpret_cast<const u32x4*>(&P[w][ra*64 + sa*8]));
        oacc[tm][0] = __builtin_amdgcn_mfma_f32_16x16x32_bf16(pf, vf[0], oacc[tm][0], 0,0,0);
        oacc[tm][1] = __builtin_amdgcn_mfma_f32_16x16x32_bf16(pf, vf[1], oacc[tm][1], 0,0,0);
      }
    }
  }
  // normalize + write O bf16 [s*256+n][h*32+dh]
#pragma unroll
  for (int tm=0;tm<4;tm++){
#pragma unroll
    for (int rr=0;rr<4;rr++){
      int n = 64*w + tm*16 + lg*4 + rr;
      float inv = 1.0f / lrun[tm][rr];
      size_t rowb = (size_t)(s*256 + n)*256 + h*32;
#pragma unroll
      for (int dt=0;dt<2;dt++)
        O[rowb + dt*16 + lr] = f2bf(oacc[tm][dt][rr]*inv);
    }
  }
}

// ---------------- K4: out-proj + bias + residual + LayerNorm ----------------
__global__ __launch_bounds__(256) void k_out_ln(const u16* __restrict__ A,
        const u16* __restrict__ Wo, const float* __restrict__ bo,
        const float* __restrict__ msa, const float* __restrict__ gamma,
        const float* __restrict__ beta, float* __restrict__ out){
  __shared__ __align__(16) u16 Al[64*64];
  __shared__ float redS[64][4];
  __shared__ float redQ[64][4];
  const int tid = threadIdx.x;
  const int w = tid>>6, l = tid&63;
  const int lr = l&15, lg = l>>4;
  const int m0 = blockIdx.x*64;
  f32x4 acc[4][4] = {};
  for (int kt=0;kt<4;kt++){
    const int k0 = kt*64;
    __syncthreads();
#pragma unroll
    for (int i=0;i<2;i++){
      int flat = tid + 256*i;
      int r = flat>>3, sl = flat&7;
      u32x4 d = *reinterpret_cast<const u32x4*>(A + (size_t)(m0+r)*256 + k0 + sl*8);
      *reinterpret_cast<u32x4*>(&Al[r*64 + ((sl^(r&7))*8)]) = d;
    }
    __syncthreads();
#pragma unroll
    for (int ks=0;ks<2;ks++){
      bf16x8 af[4], bfr[4];
#pragma unroll
      for (int t=0;t<4;t++){
        int ra = t*16 + lr;
        int sa = (ks*4+lg) ^ (ra&7);
        af[t] = __builtin_bit_cast(bf16x8, *reinterpret_cast<const u32x4*>(&Al[ra*64 + sa*8]));
        int c = w*64 + t*16 + lr;
        bfr[t] = ldfrag_g(Wo + (size_t)c*256 + k0 + ks*32 + lg*8);
      }
#pragma unroll
      for (int tm=0;tm<4;tm++)
#pragma unroll
        for (int tn=0;tn<4;tn++)
          acc[tm][tn] = __builtin_amdgcn_mfma_f32_16x16x32_bf16(af[tm], bfr[tn], acc[tm][tn], 0,0,0);
    }
  }
  // + bout + residual(msa)
#pragma unroll
  for (int tn=0;tn<4;tn++){
    int c = w*64 + tn*16 + lr;
    float bc = bo[c];
#pragma unroll
    for (int tm=0;tm<4;tm++)
#pragma unroll
      for (int rr=0;rr<4;rr++){
        int m = m0 + tm*16 + lg*4 + rr;
        acc[tm][tn][rr] += bc + msa[(size_t)m*256 + c];
      }
  }
  // LN: per-wave partial sums -> LDS -> combine
#pragma unroll
  for (int tm=0;tm<4;tm++){
#pragma unroll
    for (int rr=0;rr<4;rr++){
      float sS = 0.f, sQ = 0.f;
#pragma unroll
      for (int tn=0;tn<4;tn++){
        float v = acc[tm][tn][rr];
        sS += v; sQ += v*v;
      }
      sS += __shfl_xor(sS,1); sS += __shfl_xor(sS,2); sS += __shfl_xor(sS,4); sS += __shfl_xor(sS,8);
      sQ += __shfl_xor(sQ,1); sQ += __shfl_xor(sQ,2); sQ += __shfl_xor(sQ,4); sQ += __shfl_xor(sQ,8);
      if (lr == 0){
        int row = tm*16 + lg*4 + rr;
        redS[row][w] = sS;
        redQ[row][w] = sQ;
      }
    }
  }
  __syncthreads();
#pragma unroll
  for (int tm=0;tm<4;tm++){
#pragma unroll
    for (int rr=0;rr<4;rr++){
      int row = tm*16 + lg*4 + rr;
      float S = redS[row][0]+redS[row][1]+redS[row][2]+redS[row][3];
      float Q = redQ[row][0]+redQ[row][1]+redQ[row][2]+redQ[row][3];
      float mu = S * (1.0f/256.0f);
      float var = Q * (1.0f/256.0f) - mu*mu;
      float inv = rsqrtf(var + 1e-5f);
      int m = m0 + row;
#pragma unroll
      for (int tn=0;tn<4;tn++){
        int c = w*64 + tn*16 + lr;
        out[(size_t)m*256 + c] = (acc[tm][tn][rr]-mu)*inv*gamma[c] + beta[c];
      }
    }
  }
}

extern "C" void kernel_launch(void* const* d_in, const int* in_sizes, int n_in,
                              void* d_out, int out_size, void* d_ws, size_t ws_size,
                              hipStream_t stream) {
  const float* msa  = (const float*)d_in[0];
  const float* pair = (const float*)d_in[1];
  const int*   mask = (const int*)d_in[2];
  const float* Wqkv = (const float*)d_in[3];
  const float* bqkv = (const float*)d_in[4];
  const float* Wout = (const float*)d_in[5];
  const float* bout = (const float*)d_in[6];
  const float* Wpb  = (const float*)d_in[7];
  const float* bpb  = (const float*)d_in[8];
  const float* gamma= (const float*)d_in[9];
  const float* beta = (const float*)d_in[10];
  float* out = (float*)d_out;

  char* ws = (char*)d_ws;
  u16*   msa_bf  = (u16*)(ws);                 // 16,777,216 B
  u16*   wqkv_bf = (u16*)(ws + 16777216);      //    393,216 B
  u16*   wout_bf = (u16*)(ws + 17170432);      //    131,072 B
  float* biasb   = (float*)(ws + 17301504);    //  2,097,152 B
  u16*   qkvb    = (u16*)(ws + 19398656);      // 50,331,648 B
  u16*   Ob      = (u16*)(ws + 69730304);      // 16,777,216 B  (total 86,507,520 B)

  k_cvt<<<4096, 256, 0, stream>>>(msa,  msa_bf,  8388608/4);
  k_cvt<<<192,  256, 0, stream>>>(Wqkv, wqkv_bf, 196608/4);
  k_cvt<<<64,   256, 0, stream>>>(Wout, wout_bf, 65536/4);
  k_pair_bias<<<4096, 256, 0, stream>>>(pair, mask, Wpb, bpb, biasb);
  k_qkv<<<dim3(6,256), 256, 0, stream>>>(msa_bf, wqkv_bf, bqkv, qkvb);
  k_attn<<<dim3(8,128), 256, 0, stream>>>(qkvb, biasb, Ob);
  k_out_ln<<<512, 256, 0, stream>>>(Ob, wout_bf, bout, msa, gamma, beta, out);
}

// Round 4
// 248.167 us; speedup vs baseline: 1.0468x; 1.0468x over previous
//
#include <hip/hip_runtime.h>
#include <cstdint>
#include <cstddef>

typedef unsigned short u16;
typedef __bf16 bf16x8 __attribute__((ext_vector_type(8)));
typedef float f32x4 __attribute__((ext_vector_type(4)));
typedef unsigned int u32x4 __attribute__((ext_vector_type(4)));

#define SCALE_QK 0.17677669529663687f  // 32^-0.5

__device__ __forceinline__ u16 f2bf(float f){ return __builtin_bit_cast(u16, (__bf16)f); }
__device__ __forceinline__ float bf2f(u16 u){ unsigned v = ((unsigned)u)<<16; return __builtin_bit_cast(float, v); }
__device__ __forceinline__ bf16x8 ldfrag_g(const u16* p){
  return __builtin_bit_cast(bf16x8, *reinterpret_cast<const u32x4*>(p));
}
// async global->LDS, 16B per lane; lds base must be wave-uniform
__device__ __forceinline__ void gload16(const u16* g, u16* lds){
  __builtin_amdgcn_global_load_lds((const __attribute__((address_space(1))) unsigned int*)g,
                                   (__attribute__((address_space(3))) unsigned int*)lds, 16, 0, 0);
}

// ---------------- K0: f32 -> bf16 convert (msa) ----------------
__global__ __launch_bounds__(256) void k_cvt(const float* __restrict__ src,
                                             u16* __restrict__ dst, int n4){
  int stride = gridDim.x * blockDim.x;
  for (int idx = blockIdx.x*blockDim.x + threadIdx.x; idx < n4; idx += stride){
    float4 v = reinterpret_cast<const float4*>(src)[idx];
    ushort4 o;
    o.x = f2bf(v.x); o.y = f2bf(v.y); o.z = f2bf(v.z); o.w = f2bf(v.w);
    reinterpret_cast<ushort4*>(dst)[idx] = o;
  }
}

// ---------------- K0b: convert Wqkv (192 blocks) + Wout (64 blocks) ----------------
__global__ __launch_bounds__(256) void k_cvt2(const float* __restrict__ a, u16* __restrict__ da,
                                              const float* __restrict__ b, u16* __restrict__ db){
  int bid = blockIdx.x;
  if (bid < 192){
    int idx = bid*256 + threadIdx.x;
    float4 v = reinterpret_cast<const float4*>(a)[idx];
    ushort4 o; o.x=f2bf(v.x); o.y=f2bf(v.y); o.z=f2bf(v.z); o.w=f2bf(v.w);
    reinterpret_cast<ushort4*>(da)[idx] = o;
  } else {
    int idx = (bid-192)*256 + threadIdx.x;
    float4 v = reinterpret_cast<const float4*>(b)[idx];
    ushort4 o; o.x=f2bf(v.x); o.y=f2bf(v.y); o.z=f2bf(v.z); o.w=f2bf(v.w);
    reinterpret_cast<ushort4*>(db)[idx] = o;
  }
}

// ---------------- K1: pair bias + mask -> biasT[h][m][n] bf16 ----------------
__global__ __launch_bounds__(256) void k_pair_bias(const float* __restrict__ pair,
        const int* __restrict__ mask, const float* __restrict__ Wpb,
        const float* __restrict__ bpb, u16* __restrict__ bT){
  __shared__ float wsm[8][128];
  __shared__ float bsm[8];
  int tid = threadIdx.x;
  for (int i = tid; i < 1024; i += 256) wsm[i>>7][i&127] = Wpb[i];
  if (tid < 8) bsm[tid] = bpb[tid];
  __syncthreads();
  int g = tid>>4, l = tid&15;
  int row = blockIdx.x*16 + g;             // flat n*256 + m
  const float4* p = reinterpret_cast<const float4*>(pair + (size_t)row*128);
  float4 a0 = p[l];
  float4 a1 = p[l+16];
  int c0 = 4*l, c1 = 64 + 4*l;
  float acc[8];
#pragma unroll
  for (int hh=0; hh<8; hh++){
    acc[hh] = a0.x*wsm[hh][c0] + a0.y*wsm[hh][c0+1] + a0.z*wsm[hh][c0+2] + a0.w*wsm[hh][c0+3]
            + a1.x*wsm[hh][c1] + a1.y*wsm[hh][c1+1] + a1.z*wsm[hh][c1+2] + a1.w*wsm[hh][c1+3];
  }
#pragma unroll
  for (int hh=0; hh<8; hh++){
    float v = acc[hh];
    v += __shfl_xor(v,1); v += __shfl_xor(v,2); v += __shfl_xor(v,4); v += __shfl_xor(v,8);
    acc[hh] = v;
  }
  if (l == 0){
    float mb = (mask[row] == 0) ? -1e9f : 0.0f;
    int n = row>>8, m = row&255;
#pragma unroll
    for (int hh=0; hh<8; hh++)
      bT[hh*65536 + m*256 + n] = f2bf(acc[hh] + bsm[hh] + mb);
  }
}

// ---------------- K2: QKV GEMM (32768x768x256) with global_load_lds staging ----------------
__global__ __launch_bounds__(256, 3) void k_qkv(const u16* __restrict__ A,
                                                const u16* __restrict__ B,
                                                const float* __restrict__ bq,
                                                u16* __restrict__ qkv){
  __shared__ __align__(16) u16 Al[128*64];
  __shared__ __align__(16) u16 Bl[128*64];
  const int tid = threadIdx.x;
  const int w = tid>>6, l = tid&63;
  const int wm = w>>1, wn = w&1;
  const int m0 = blockIdx.y*128, n0 = blockIdx.x*128;
  const int lr = l&15, lg = l>>4;
  f32x4 acc[4][4] = {};
  for (int kt=0; kt<4; ++kt){
    const int k0 = kt*64;
    __syncthreads();
    // each wave stages 32 rows of Al and Bl: 4 wave-loads each, pre-swizzled source
#pragma unroll
    for (int j=0;j<4;j++){
      int ch = w*256 + j*64 + l;          // chunk id 0..1023
      int r = ch>>3, sl = ch&7;
      gload16(A + (size_t)(m0+r)*256 + k0 + ((sl^(r&7))*8), Al + (size_t)(w*256 + j*64)*8);
      gload16(B + (size_t)(n0+r)*256 + k0 + ((sl^(r&7))*8), Bl + (size_t)(w*256 + j*64)*8);
    }
    __syncthreads();
#pragma unroll
    for (int ks=0; ks<2; ++ks){
      bf16x8 af[4], bfr[4];
#pragma unroll
      for (int t=0;t<4;t++){
        int ra = wm*64 + t*16 + lr;
        int sa = (ks*4 + lg) ^ (ra&7);
        af[t] = __builtin_bit_cast(bf16x8, *reinterpret_cast<const u32x4*>(&Al[ra*64 + sa*8]));
        int rb = wn*64 + t*16 + lr;
        int sb = (ks*4 + lg) ^ (rb&7);
        bfr[t] = __builtin_bit_cast(bf16x8, *reinterpret_cast<const u32x4*>(&Bl[rb*64 + sb*8]));
      }
#pragma unroll
      for (int tm=0;tm<4;tm++)
#pragma unroll
        for (int tn=0;tn<4;tn++)
          acc[tm][tn] = __builtin_amdgcn_mfma_f32_16x16x32_bf16(af[tm], bfr[tn], acc[tm][tn], 0,0,0);
    }
  }
#pragma unroll
  for (int tn=0;tn<4;tn++){
    int c = n0 + wn*64 + tn*16 + lr;       // 0..767
    int t3 = c>>8, hh = (c>>5)&7, dh = c&31;
    float bb = bq[c];
    u16* obase = qkv + (size_t)(t3*8+hh)*32768*32 + dh;
#pragma unroll
    for (int tm=0;tm<4;tm++){
#pragma unroll
      for (int rr=0;rr<4;rr++){
        int m = m0 + wm*64 + tm*16 + lg*4 + rr;
        obase[(size_t)m*32] = f2bf(acc[tm][tn][rr] + bb);
      }
    }
  }
}

// ---------------- K3: attention; block = (h, s, n-half), wave = 32 q-rows ----------------
__global__ __launch_bounds__(256, 3) void k_attn(const u16* __restrict__ qkv,
                                                 const u16* __restrict__ bT,
                                                 u16* __restrict__ O){
  __shared__ __align__(16) u16 vT[32*256];     // [dh][m] swizzled, 16KB
  __shared__ __align__(16) u16 P[4][32*64];    // per-wave P tile, 16KB
  const int h = blockIdx.x, s = blockIdx.y, z = blockIdx.z;
  const int tid = threadIdx.x;
  const int w = tid>>6, l = tid&63;
  const int lr = l&15, lg = l>>4;
  const int n0 = z*128 + 32*w;                 // this wave's first q-row
  const u16* qb = qkv + ((size_t)h*32768 + s*256)*32;
  const u16* kb = qkv + ((size_t)(8+h)*32768 + s*256)*32;
  const u16* vb = qkv + ((size_t)(16+h)*32768 + s*256)*32;
  const u16* bb = bT + h*65536;

  // stage V transposed: vT[dh][m]
#pragma unroll
  for (int i=0;i<4;i++){
    int flat4 = tid + 256*i;                 // 1024 chunks of 8 elems
    int m = flat4>>2, d0 = (flat4&3)*8;
    u32x4 d = *reinterpret_cast<const u32x4*>(vb + (size_t)m*32 + d0);
    u16 tmp[8];
    *reinterpret_cast<u32x4*>(tmp) = d;
#pragma unroll
    for (int j=0;j<8;j++){
      int dh = d0 + j;
      vT[dh*256 + (((m>>3)^(dh&7))*8) + (m&7)] = tmp[j];
    }
  }
  __syncthreads();

  bf16x8 qf[2];
#pragma unroll
  for (int t=0;t<2;t++)
    qf[t] = ldfrag_g(qb + (size_t)(n0 + t*16 + lr)*32 + lg*8);

  f32x4 oacc[2][2] = {};
  float mrun[2][4], lrun[2][4];
#pragma unroll
  for (int t=0;t<2;t++)
#pragma unroll
    for (int rr=0;rr<4;rr++){ mrun[t][rr] = -3e38f; lrun[t][rr] = 0.f; }

  for (int mt=0; mt<4; ++mt){
    // issue bias loads early (bf16, transposed layout: 4 rr contiguous per lane)
    ushort4 b4[2][4];
#pragma unroll
    for (int t=0;t<2;t++)
#pragma unroll
      for (int tn=0;tn<4;tn++)
        b4[t][tn] = *reinterpret_cast<const ushort4*>(
            bb + (size_t)(mt*64 + tn*16 + lr)*256 + n0 + t*16 + lg*4);
    bf16x8 kf[4];
#pragma unroll
    for (int tn=0;tn<4;tn++)
      kf[tn] = ldfrag_g(kb + (size_t)(mt*64 + tn*16 + lr)*32 + lg*8);
    f32x4 sacc[2][4] = {};
#pragma unroll
    for (int t=0;t<2;t++)
#pragma unroll
      for (int tn=0;tn<4;tn++)
        sacc[t][tn] = __builtin_amdgcn_mfma_f32_16x16x32_bf16(qf[t], kf[tn], sacc[t][tn], 0,0,0);
    // scale + bias
#pragma unroll
    for (int t=0;t<2;t++)
#pragma unroll
      for (int tn=0;tn<4;tn++){
        float bc[4] = { bf2f(b4[t][tn].x), bf2f(b4[t][tn].y), bf2f(b4[t][tn].z), bf2f(b4[t][tn].w) };
#pragma unroll
        for (int rr=0;rr<4;rr++)
          sacc[t][tn][rr] = sacc[t][tn][rr]*SCALE_QK + bc[rr];
      }
    // online softmax per row (t, rr); reduce over m = lanes lr + tiles tn
#pragma unroll
    for (int t=0;t<2;t++){
#pragma unroll
      for (int rr=0;rr<4;rr++){
        float mx = fmaxf(fmaxf(sacc[t][0][rr], sacc[t][1][rr]),
                         fmaxf(sacc[t][2][rr], sacc[t][3][rr]));
        mx = fmaxf(mx, __shfl_xor(mx,1));
        mx = fmaxf(mx, __shfl_xor(mx,2));
        mx = fmaxf(mx, __shfl_xor(mx,4));
        mx = fmaxf(mx, __shfl_xor(mx,8));
        float mo = mrun[t][rr];
        float mn = fmaxf(mo, mx);
        float corr = __expf(mo - mn);
        mrun[t][rr] = mn;
        float ps = 0.f;
#pragma unroll
        for (int tn=0;tn<4;tn++){
          float p = __expf(sacc[t][tn][rr] - mn);
          sacc[t][tn][rr] = p;
          ps += p;
        }
        ps += __shfl_xor(ps,1);
        ps += __shfl_xor(ps,2);
        ps += __shfl_xor(ps,4);
        ps += __shfl_xor(ps,8);
        lrun[t][rr] = lrun[t][rr]*corr + ps;
        oacc[t][0][rr] *= corr;
        oacc[t][1][rr] *= corr;
      }
    }
    // write P (bf16) to per-wave LDS, swizzled
#pragma unroll
    for (int t=0;t<2;t++){
#pragma unroll
      for (int rr=0;rr<4;rr++){
        int row = t*16 + lg*4 + rr;          // 0..31
        int rb = row*64;
        int sx = row&7;
#pragma unroll
        for (int tn=0;tn<4;tn++){
          int col = tn*16 + lr;
          P[w][rb + (((col>>3)^sx)*8) + (col&7)] = f2bf(sacc[t][tn][rr]);
        }
      }
    }
    // PV
#pragma unroll
    for (int kk=0;kk<2;kk++){
      bf16x8 vf[2];
#pragma unroll
      for (int dt=0;dt<2;dt++){
        int c = dt*16 + lr;
        int slot = (mt*8 + kk*4 + lg) ^ (c&7);
        vf[dt] = __builtin_bit_cast(bf16x8, *reinterpret_cast<const u32x4*>(&vT[c*256 + slot*8]));
      }
#pragma unroll
      for (int t=0;t<2;t++){
        int ra = t*16 + lr;
        int sa = (kk*4 + lg) ^ (ra&7);
        bf16x8 pf = __builtin_bit_cast(bf16x8, *reinterpret_cast<const u32x4*>(&P[w][ra*64 + sa*8]));
        oacc[t][0] = __builtin_amdgcn_mfma_f32_16x16x32_bf16(pf, vf[0], oacc[t][0], 0,0,0);
        oacc[t][1] = __builtin_amdgcn_mfma_f32_16x16x32_bf16(pf, vf[1], oacc[t][1], 0,0,0);
      }
    }
  }
  // normalize + write O bf16 [s*256+n][h*32+dh]
#pragma unroll
  for (int t=0;t<2;t++){
#pragma unroll
    for (int rr=0;rr<4;rr++){
      int n = n0 + t*16 + lg*4 + rr;
      float inv = 1.0f / lrun[t][rr];
      size_t rowb = (size_t)(s*256 + n)*256 + h*32;
#pragma unroll
      for (int dt=0;dt<2;dt++)
        O[rowb + dt*16 + lr] = f2bf(oacc[t][dt][rr]*inv);
    }
  }
}

// ---------------- K4: out-proj + bias + residual + LayerNorm ----------------
__global__ __launch_bounds__(256, 3) void k_out_ln(const u16* __restrict__ A,
        const u16* __restrict__ Wo, const float* __restrict__ bo,
        const float* __restrict__ msa, const float* __restrict__ gamma,
        const float* __restrict__ beta, float* __restrict__ out){
  __shared__ __align__(16) u16 Al[64*64];      // 8KB
  __shared__ __align__(16) u16 Wl[256*64];     // 32KB
  __shared__ float redS[64][4];
  __shared__ float redQ[64][4];
  const int tid = threadIdx.x;
  const int w = tid>>6, l = tid&63;
  const int lr = l&15, lg = l>>4;
  const int m0 = blockIdx.x*64;
  f32x4 acc[4][4] = {};
  for (int kt=0;kt<4;kt++){
    const int k0 = kt*64;
    __syncthreads();
    // stage A rows (64): 512 chunks; 2 wave-loads per wave
#pragma unroll
    for (int j=0;j<2;j++){
      int ch = w*128 + j*64 + l;
      int r = ch>>3, sl = ch&7;
      gload16(A + (size_t)(m0+r)*256 + k0 + ((sl^(r&7))*8), Al + (size_t)(w*128 + j*64)*8);
    }
    // stage Wo rows (256): 2048 chunks; 8 wave-loads per wave
#pragma unroll
    for (int j=0;j<8;j++){
      int ch = w*512 + j*64 + l;
      int r = ch>>3, sl = ch&7;
      gload16(Wo + (size_t)r*256 + k0 + ((sl^(r&7))*8), Wl + (size_t)(w*512 + j*64)*8);
    }
    __syncthreads();
#pragma unroll
    for (int ks=0;ks<2;ks++){
      bf16x8 af[4], bfr[4];
#pragma unroll
      for (int t=0;t<4;t++){
        int ra = t*16 + lr;
        int sa = (ks*4+lg) ^ (ra&7);
        af[t] = __builtin_bit_cast(bf16x8, *reinterpret_cast<const u32x4*>(&Al[ra*64 + sa*8]));
        int rb = w*64 + t*16 + lr;
        int sb = (ks*4+lg) ^ (rb&7);
        bfr[t] = __builtin_bit_cast(bf16x8, *reinterpret_cast<const u32x4*>(&Wl[rb*64 + sb*8]));
      }
#pragma unroll
      for (int tm=0;tm<4;tm++)
#pragma unroll
        for (int tn=0;tn<4;tn++)
          acc[tm][tn] = __builtin_amdgcn_mfma_f32_16x16x32_bf16(af[tm], bfr[tn], acc[tm][tn], 0,0,0);
    }
  }
  // + bout + residual(msa)
#pragma unroll
  for (int tn=0;tn<4;tn++){
    int c = w*64 + tn*16 + lr;
    float bc = bo[c];
#pragma unroll
    for (int tm=0;tm<4;tm++)
#pragma unroll
      for (int rr=0;rr<4;rr++){
        int m = m0 + tm*16 + lg*4 + rr;
        acc[tm][tn][rr] += bc + msa[(size_t)m*256 + c];
      }
  }
  // LN reduce
#pragma unroll
  for (int tm=0;tm<4;tm++){
#pragma unroll
    for (int rr=0;rr<4;rr++){
      float sS = 0.f, sQ = 0.f;
#pragma unroll
      for (int tn=0;tn<4;tn++){
        float v = acc[tm][tn][rr];
        sS += v; sQ += v*v;
      }
      sS += __shfl_xor(sS,1); sS += __shfl_xor(sS,2); sS += __shfl_xor(sS,4); sS += __shfl_xor(sS,8);
      sQ += __shfl_xor(sQ,1); sQ += __shfl_xor(sQ,2); sQ += __shfl_xor(sQ,4); sQ += __shfl_xor(sQ,8);
      if (lr == 0){
        int row = tm*16 + lg*4 + rr;
        redS[row][w] = sS;
        redQ[row][w] = sQ;
      }
    }
  }
  __syncthreads();
#pragma unroll
  for (int tm=0;tm<4;tm++){
#pragma unroll
    for (int rr=0;rr<4;rr++){
      int row = tm*16 + lg*4 + rr;
      float S = redS[row][0]+redS[row][1]+redS[row][2]+redS[row][3];
      float Q = redQ[row][0]+redQ[row][1]+redQ[row][2]+redQ[row][3];
      float mu = S * (1.0f/256.0f);
      float var = Q * (1.0f/256.0f) - mu*mu;
      float inv = rsqrtf(var + 1e-5f);
      int m = m0 + row;
#pragma unroll
      for (int tn=0;tn<4;tn++){
        int c = w*64 + tn*16 + lr;
        out[(size_t)m*256 + c] = (acc[tm][tn][rr]-mu)*inv*gamma[c] + beta[c];
      }
    }
  }
}

extern "C" void kernel_launch(void* const* d_in, const int* in_sizes, int n_in,
                              void* d_out, int out_size, void* d_ws, size_t ws_size,
                              hipStream_t stream) {
  const float* msa  = (const float*)d_in[0];
  const float* pair = (const float*)d_in[1];
  const int*   mask = (const int*)d_in[2];
  const float* Wqkv = (const float*)d_in[3];
  const float* bqkv = (const float*)d_in[4];
  const float* Wout = (const float*)d_in[5];
  const float* bout = (const float*)d_in[6];
  const float* Wpb  = (const float*)d_in[7];
  const float* bpb  = (const float*)d_in[8];
  const float* gamma= (const float*)d_in[9];
  const float* beta = (const float*)d_in[10];
  float* out = (float*)d_out;

  char* ws = (char*)d_ws;
  u16*   msa_bf  = (u16*)(ws);                 // 16,777,216 B
  u16*   wqkv_bf = (u16*)(ws + 16777216);      //    393,216 B
  u16*   wout_bf = (u16*)(ws + 17170432);      //    131,072 B
  u16*   biasT   = (u16*)(ws + 17301504);      //  1,048,576 B  bf16 [h][m][n]
  u16*   qkvb    = (u16*)(ws + 18350080);      // 50,331,648 B
  u16*   Ob      = (u16*)(ws + 68681728);      // 16,777,216 B  (total 85,458,944 B)

  k_cvt<<<4096, 256, 0, stream>>>(msa, msa_bf, 8388608/4);
  k_cvt2<<<256, 256, 0, stream>>>(Wqkv, wqkv_bf, Wout, wout_bf);
  k_pair_bias<<<4096, 256, 0, stream>>>(pair, mask, Wpb, bpb, biasT);
  k_qkv<<<dim3(6,256), 256, 0, stream>>>(msa_bf, wqkv_bf, bqkv, qkvb);
  k_attn<<<dim3(8,128,2), 256, 0, stream>>>(qkvb, biasT, Ob);
  k_out_ln<<<512, 256, 0, stream>>>(Ob, wout_bf, bout, msa, gamma, beta, out);
}

// Round 7
// 233.400 us; speedup vs baseline: 1.1130x; 1.0633x over previous
//
#include <hip/hip_runtime.h>
#include <cstdint>
#include <cstddef>

typedef unsigned short u16;
typedef __bf16 bf16x8 __attribute__((ext_vector_type(8)));
typedef float f32x4 __attribute__((ext_vector_type(4)));
typedef unsigned int u32x4 __attribute__((ext_vector_type(4)));

// SCALE and pair-bias are pre-divided by ln2 so softmax can use exp2 directly.
#define SCALE_QK_LOG2 0.25509904f   // 32^-0.5 / ln(2)
#define INV_LN2 1.4426950408889634f

__device__ __forceinline__ u16 f2bf(float f){ return __builtin_bit_cast(u16, (__bf16)f); }
__device__ __forceinline__ float bf2f(u16 u){ unsigned v = ((unsigned)u)<<16; return __builtin_bit_cast(float, v); }
__device__ __forceinline__ bf16x8 ldfrag_g(const u16* p){
  return __builtin_bit_cast(bf16x8, *reinterpret_cast<const u32x4*>(p));
}
// async global->LDS, 16B per lane; lds base must be wave-uniform
__device__ __forceinline__ void gload16(const u16* g, u16* lds){
  __builtin_amdgcn_global_load_lds((const __attribute__((address_space(1))) unsigned int*)g,
                                   (__attribute__((address_space(3))) unsigned int*)lds, 16, 0, 0);
}

// ---------------- K0: f32 -> bf16 convert (msa) ----------------
__global__ __launch_bounds__(256) void k_cvt(const float* __restrict__ src,
                                             u16* __restrict__ dst, int n4){
  int stride = gridDim.x * blockDim.x;
  for (int idx = blockIdx.x*blockDim.x + threadIdx.x; idx < n4; idx += stride){
    float4 v = reinterpret_cast<const float4*>(src)[idx];
    ushort4 o;
    o.x = f2bf(v.x); o.y = f2bf(v.y); o.z = f2bf(v.z); o.w = f2bf(v.w);
    reinterpret_cast<ushort4*>(dst)[idx] = o;
  }
}

// ---------------- K0b: convert Wqkv (192 blocks) + Wout (64 blocks) ----------------
__global__ __launch_bounds__(256) void k_cvt2(const float* __restrict__ a, u16* __restrict__ da,
                                              const float* __restrict__ b, u16* __restrict__ db){
  int bid = blockIdx.x;
  if (bid < 192){
    int idx = bid*256 + threadIdx.x;
    float4 v = reinterpret_cast<const float4*>(a)[idx];
    ushort4 o; o.x=f2bf(v.x); o.y=f2bf(v.y); o.z=f2bf(v.z); o.w=f2bf(v.w);
    reinterpret_cast<ushort4*>(da)[idx] = o;
  } else {
    int idx = (bid-192)*256 + threadIdx.x;
    float4 v = reinterpret_cast<const float4*>(b)[idx];
    ushort4 o; o.x=f2bf(v.x); o.y=f2bf(v.y); o.z=f2bf(v.z); o.w=f2bf(v.w);
    reinterpret_cast<ushort4*>(db)[idx] = o;
  }
}

// ---------------- K1: pair bias + mask -> biasT[h][m][n] bf16, pre-scaled by 1/ln2 ----------------
__global__ __launch_bounds__(256) void k_pair_bias(const float* __restrict__ pair,
        const int* __restrict__ mask, const float* __restrict__ Wpb,
        const float* __restrict__ bpb, u16* __restrict__ bT){
  __shared__ float wsm[8][128];
  __shared__ float bsm[8];
  int tid = threadIdx.x;
  for (int i = tid; i < 1024; i += 256) wsm[i>>7][i&127] = Wpb[i];
  if (tid < 8) bsm[tid] = bpb[tid];
  __syncthreads();
  int g = tid>>4, l = tid&15;
  int row = blockIdx.x*16 + g;             // flat n*256 + m
  const float4* p = reinterpret_cast<const float4*>(pair + (size_t)row*128);
  float4 a0 = p[l];
  float4 a1 = p[l+16];
  int c0 = 4*l, c1 = 64 + 4*l;
  float acc[8];
#pragma unroll
  for (int hh=0; hh<8; hh++){
    acc[hh] = a0.x*wsm[hh][c0] + a0.y*wsm[hh][c0+1] + a0.z*wsm[hh][c0+2] + a0.w*wsm[hh][c0+3]
            + a1.x*wsm[hh][c1] + a1.y*wsm[hh][c1+1] + a1.z*wsm[hh][c1+2] + a1.w*wsm[hh][c1+3];
  }
#pragma unroll
  for (int hh=0; hh<8; hh++){
    float v = acc[hh];
    v += __shfl_xor(v,1); v += __shfl_xor(v,2); v += __shfl_xor(v,4); v += __shfl_xor(v,8);
    acc[hh] = v;
  }
  if (l == 0){
    float mb = (mask[row] == 0) ? -1e9f : 0.0f;
    int n = row>>8, m = row&255;
#pragma unroll
    for (int hh=0; hh<8; hh++)
      bT[hh*65536 + m*256 + n] = f2bf((acc[hh] + bsm[hh] + mb) * INV_LN2);
  }
}

// ---------------- K2: QKV GEMM (32768x768x256) with global_load_lds staging ----------------
__global__ __launch_bounds__(256, 3) void k_qkv(const u16* __restrict__ A,
                                                const u16* __restrict__ B,
                                                const float* __restrict__ bq,
                                                u16* __restrict__ qkv){
  __shared__ __align__(16) u16 Al[128*64];
  __shared__ __align__(16) u16 Bl[128*64];
  const int tid = threadIdx.x;
  const int w = tid>>6, l = tid&63;
  const int wm = w>>1, wn = w&1;
  const int m0 = blockIdx.y*128, n0 = blockIdx.x*128;
  const int lr = l&15, lg = l>>4;
  f32x4 acc[4][4] = {};
  for (int kt=0; kt<4; ++kt){
    const int k0 = kt*64;
    __syncthreads();
#pragma unroll
    for (int j=0;j<4;j++){
      int ch = w*256 + j*64 + l;          // chunk id 0..1023
      int r = ch>>3, sl = ch&7;
      gload16(A + (size_t)(m0+r)*256 + k0 + ((sl^(r&7))*8), Al + (size_t)(w*256 + j*64)*8);
      gload16(B + (size_t)(n0+r)*256 + k0 + ((sl^(r&7))*8), Bl + (size_t)(w*256 + j*64)*8);
    }
    __syncthreads();
#pragma unroll
    for (int ks=0; ks<2; ++ks){
      bf16x8 af[4], bfr[4];
#pragma unroll
      for (int t=0;t<4;t++){
        int ra = wm*64 + t*16 + lr;
        int sa = (ks*4 + lg) ^ (ra&7);
        af[t] = __builtin_bit_cast(bf16x8, *reinterpret_cast<const u32x4*>(&Al[ra*64 + sa*8]));
        int rb = wn*64 + t*16 + lr;
        int sb = (ks*4 + lg) ^ (rb&7);
        bfr[t] = __builtin_bit_cast(bf16x8, *reinterpret_cast<const u32x4*>(&Bl[rb*64 + sb*8]));
      }
#pragma unroll
      for (int tm=0;tm<4;tm++)
#pragma unroll
        for (int tn=0;tn<4;tn++)
          acc[tm][tn] = __builtin_amdgcn_mfma_f32_16x16x32_bf16(af[tm], bfr[tn], acc[tm][tn], 0,0,0);
    }
  }
#pragma unroll
  for (int tn=0;tn<4;tn++){
    int c = n0 + wn*64 + tn*16 + lr;       // 0..767
    int t3 = c>>8, hh = (c>>5)&7, dh = c&31;
    float bb = bq[c];
    u16* obase = qkv + (size_t)(t3*8+hh)*32768*32 + dh;
#pragma unroll
    for (int tm=0;tm<4;tm++){
#pragma unroll
      for (int rr=0;rr<4;rr++){
        int m = m0 + wm*64 + tm*16 + lg*4 + rr;
        obase[(size_t)m*32] = f2bf(acc[tm][tn][rr] + bb);
      }
    }
  }
}

// ---------------- K3: attention; single-pass softmax over all 256 keys in registers ----------------
__global__ __launch_bounds__(256, 2) void k_attn(const u16* __restrict__ qkv,
                                                 const u16* __restrict__ bT,
                                                 u16* __restrict__ O){
  __shared__ __align__(16) u16 vT[32*256];     // [dh][m] swizzled, 16KB
  __shared__ __align__(16) u16 P[4][32*64];    // per-wave P chunk (64 keys), 16KB
  const int h = blockIdx.x, s = blockIdx.y, z = blockIdx.z;
  const int tid = threadIdx.x;
  const int w = tid>>6, l = tid&63;
  const int lr = l&15, lg = l>>4;
  const int n0 = z*128 + 32*w;                 // this wave's first q-row
  const u16* qb = qkv + ((size_t)h*32768 + s*256)*32;
  const u16* kb = qkv + ((size_t)(8+h)*32768 + s*256)*32;
  const u16* vb = qkv + ((size_t)(16+h)*32768 + s*256)*32;
  const u16* bb = bT + h*65536;

  // stage V transposed: vT[dh][m]
#pragma unroll
  for (int i=0;i<4;i++){
    int flat4 = tid + 256*i;                 // 1024 chunks of 8 elems
    int m = flat4>>2, d0 = (flat4&3)*8;
    u32x4 d = *reinterpret_cast<const u32x4*>(vb + (size_t)m*32 + d0);
    u16 tmp[8];
    *reinterpret_cast<u32x4*>(tmp) = d;
#pragma unroll
    for (int j=0;j<8;j++){
      int dh = d0 + j;
      vT[dh*256 + (((m>>3)^(dh&7))*8) + (m&7)] = tmp[j];
    }
  }
  __syncthreads();

  bf16x8 qf[2];
#pragma unroll
  for (int t=0;t<2;t++)
    qf[t] = ldfrag_g(qb + (size_t)(n0 + t*16 + lr)*32 + lg*8);

  // ---- QK^T: all 256 keys into registers ----
  f32x4 sacc[2][16] = {};
#pragma unroll
  for (int kt=0; kt<4; ++kt){
    bf16x8 kf[4];
#pragma unroll
    for (int tn=0;tn<4;tn++)
      kf[tn] = ldfrag_g(kb + (size_t)(kt*64 + tn*16 + lr)*32 + lg*8);
#pragma unroll
    for (int t=0;t<2;t++)
#pragma unroll
      for (int tn=0;tn<4;tn++)
        sacc[t][kt*4+tn] = __builtin_amdgcn_mfma_f32_16x16x32_bf16(qf[t], kf[tn], sacc[t][kt*4+tn], 0,0,0);
  }

  // ---- scale (log2 domain) + bias ----
#pragma unroll
  for (int kt=0;kt<4;kt++){
#pragma unroll
    for (int t=0;t<2;t++)
#pragma unroll
      for (int tn=0;tn<4;tn++){
        ushort4 b4 = *reinterpret_cast<const ushort4*>(
            bb + (size_t)(kt*64 + tn*16 + lr)*256 + n0 + t*16 + lg*4);
        float bc[4] = { bf2f(b4.x), bf2f(b4.y), bf2f(b4.z), bf2f(b4.w) };
#pragma unroll
        for (int rr=0;rr<4;rr++)
          sacc[t][kt*4+tn][rr] = sacc[t][kt*4+tn][rr]*SCALE_QK_LOG2 + bc[rr];
      }
  }

  // ---- single-pass softmax: max/sum over all 16 reg-tiles + 16 lanes ----
  float inv_l[2][4];
#pragma unroll
  for (int t=0;t<2;t++){
#pragma unroll
    for (int rr=0;rr<4;rr++){
      float mx = sacc[t][0][rr];
#pragma unroll
      for (int j=1;j<16;j++) mx = fmaxf(mx, sacc[t][j][rr]);
      mx = fmaxf(mx, __shfl_xor(mx,1));
      mx = fmaxf(mx, __shfl_xor(mx,2));
      mx = fmaxf(mx, __shfl_xor(mx,4));
      mx = fmaxf(mx, __shfl_xor(mx,8));
      float ps = 0.f;
#pragma unroll
      for (int j=0;j<16;j++){
        float p = __builtin_amdgcn_exp2f(sacc[t][j][rr] - mx);
        sacc[t][j][rr] = p;
        ps += p;
      }
      ps += __shfl_xor(ps,1);
      ps += __shfl_xor(ps,2);
      ps += __shfl_xor(ps,4);
      ps += __shfl_xor(ps,8);
      inv_l[t][rr] = 1.0f / ps;
    }
  }

  // ---- PV: per 64-key chunk through per-wave LDS (P transpose), no rescale needed ----
  f32x4 oacc[2][2] = {};
#pragma unroll
  for (int mt=0; mt<4; ++mt){
#pragma unroll
    for (int t=0;t<2;t++){
#pragma unroll
      for (int rr=0;rr<4;rr++){
        int row = t*16 + lg*4 + rr;          // 0..31
        int rb = row*64;
        int sx = row&7;
#pragma unroll
        for (int tn=0;tn<4;tn++){
          int col = tn*16 + lr;
          P[w][rb + (((col>>3)^sx)*8) + (col&7)] = f2bf(sacc[t][mt*4+tn][rr]);
        }
      }
    }
#pragma unroll
    for (int kk=0;kk<2;kk++){
      bf16x8 vf[2];
#pragma unroll
      for (int dt=0;dt<2;dt++){
        int c = dt*16 + lr;
        int slot = (mt*8 + kk*4 + lg) ^ (c&7);
        vf[dt] = __builtin_bit_cast(bf16x8, *reinterpret_cast<const u32x4*>(&vT[c*256 + slot*8]));
      }
#pragma unroll
      for (int t=0;t<2;t++){
        int ra = t*16 + lr;
        int sa = (kk*4 + lg) ^ (ra&7);
        bf16x8 pf = __builtin_bit_cast(bf16x8, *reinterpret_cast<const u32x4*>(&P[w][ra*64 + sa*8]));
        oacc[t][0] = __builtin_amdgcn_mfma_f32_16x16x32_bf16(pf, vf[0], oacc[t][0], 0,0,0);
        oacc[t][1] = __builtin_amdgcn_mfma_f32_16x16x32_bf16(pf, vf[1], oacc[t][1], 0,0,0);
      }
    }
  }
  // normalize + write O bf16 [s*256+n][h*32+dh]
#pragma unroll
  for (int t=0;t<2;t++){
#pragma unroll
    for (int rr=0;rr<4;rr++){
      int n = n0 + t*16 + lg*4 + rr;
      float inv = inv_l[t][rr];
      size_t rowb = (size_t)(s*256 + n)*256 + h*32;
#pragma unroll
      for (int dt=0;dt<2;dt++)
        O[rowb + dt*16 + lr] = f2bf(oacc[t][dt][rr]*inv);
    }
  }
}

// ---------------- K4: out-proj + bias + residual + LayerNorm ----------------
__global__ __launch_bounds__(256, 3) void k_out_ln(const u16* __restrict__ A,
        const u16* __restrict__ Wo, const float* __restrict__ bo,
        const float* __restrict__ msa, const float* __restrict__ gamma,
        const float* __restrict__ beta, float* __restrict__ out){
  __shared__ __align__(16) u16 Al[64*64];      // 8KB
  __shared__ __align__(16) u16 Wl[256*64];     // 32KB
  __shared__ float redS[64][4];
  __shared__ float redQ[64][4];
  const int tid = threadIdx.x;
  const int w = tid>>6, l = tid&63;
  const int lr = l&15, lg = l>>4;
  const int m0 = blockIdx.x*64;
  f32x4 acc[4][4] = {};
  for (int kt=0;kt<4;kt++){
    const int k0 = kt*64;
    __syncthreads();
#pragma unroll
    for (int j=0;j<2;j++){
      int ch = w*128 + j*64 + l;
      int r = ch>>3, sl = ch&7;
      gload16(A + (size_t)(m0+r)*256 + k0 + ((sl^(r&7))*8), Al + (size_t)(w*128 + j*64)*8);
    }
#pragma unroll
    for (int j=0;j<8;j++){
      int ch = w*512 + j*64 + l;
      int r = ch>>3, sl = ch&7;
      gload16(Wo + (size_t)r*256 + k0 + ((sl^(r&7))*8), Wl + (size_t)(w*512 + j*64)*8);
    }
    __syncthreads();
#pragma unroll
    for (int ks=0;ks<2;ks++){
      bf16x8 af[4], bfr[4];
#pragma unroll
      for (int t=0;t<4;t++){
        int ra = t*16 + lr;
        int sa = (ks*4+lg) ^ (ra&7);
        af[t] = __builtin_bit_cast(bf16x8, *reinterpret_cast<const u32x4*>(&Al[ra*64 + sa*8]));
        int rb = w*64 + t*16 + lr;
        int sb = (ks*4+lg) ^ (rb&7);
        bfr[t] = __builtin_bit_cast(bf16x8, *reinterpret_cast<const u32x4*>(&Wl[rb*64 + sb*8]));
      }
#pragma unroll
      for (int tm=0;tm<4;tm++)
#pragma unroll
        for (int tn=0;tn<4;tn++)
          acc[tm][tn] = __builtin_amdgcn_mfma_f32_16x16x32_bf16(af[tm], bfr[tn], acc[tm][tn], 0,0,0);
    }
  }
#pragma unroll
  for (int tn=0;tn<4;tn++){
    int c = w*64 + tn*16 + lr;
    float bc = bo[c];
#pragma unroll
    for (int tm=0;tm<4;tm++)
#pragma unroll
      for (int rr=0;rr<4;rr++){
        int m = m0 + tm*16 + lg*4 + rr;
        acc[tm][tn][rr] += bc + msa[(size_t)m*256 + c];
      }
  }
#pragma unroll
  for (int tm=0;tm<4;tm++){
#pragma unroll
    for (int rr=0;rr<4;rr++){
      float sS = 0.f, sQ = 0.f;
#pragma unroll
      for (int tn=0;tn<4;tn++){
        float v = acc[tm][tn][rr];
        sS += v; sQ += v*v;
      }
      sS += __shfl_xor(sS,1); sS += __shfl_xor(sS,2); sS += __shfl_xor(sS,4); sS += __shfl_xor(sS,8);
      sQ += __shfl_xor(sQ,1); sQ += __shfl_xor(sQ,2); sQ += __shfl_xor(sQ,4); sQ += __shfl_xor(sQ,8);
      if (lr == 0){
        int row = tm*16 + lg*4 + rr;
        redS[row][w] = sS;
        redQ[row][w] = sQ;
      }
    }
  }
  __syncthreads();
#pragma unroll
  for (int tm=0;tm<4;tm++){
#pragma unroll
    for (int rr=0;rr<4;rr++){
      int row = tm*16 + lg*4 + rr;
      float S = redS[row][0]+redS[row][1]+redS[row][2]+redS[row][3];
      float Q = redQ[row][0]+redQ[row][1]+redQ[row][2]+redQ[row][3];
      float mu = S * (1.0f/256.0f);
      float var = Q * (1.0f/256.0f) - mu*mu;
      float inv = rsqrtf(var + 1e-5f);
      int m = m0 + row;
#pragma unroll
      for (int tn=0;tn<4;tn++){
        int c = w*64 + tn*16 + lr;
        out[(size_t)m*256 + c] = (acc[tm][tn][rr]-mu)*inv*gamma[c] + beta[c];
      }
    }
  }
}

extern "C" void kernel_launch(void* const* d_in, const int* in_sizes, int n_in,
                              void* d_out, int out_size, void* d_ws, size_t ws_size,
                              hipStream_t stream) {
  const float* msa  = (const float*)d_in[0];
  const float* pair = (const float*)d_in[1];
  const int*   mask = (const int*)d_in[2];
  const float* Wqkv = (const float*)d_in[3];
  const float* bqkv = (const float*)d_in[4];
  const float* Wout = (const float*)d_in[5];
  const float* bout = (const float*)d_in[6];
  const float* Wpb  = (const float*)d_in[7];
  const float* bpb  = (const float*)d_in[8];
  const float* gamma= (const float*)d_in[9];
  const float* beta = (const float*)d_in[10];
  float* out = (float*)d_out;

  char* ws = (char*)d_ws;
  u16*   msa_bf  = (u16*)(ws);                 // 16,777,216 B
  u16*   wqkv_bf = (u16*)(ws + 16777216);      //    393,216 B
  u16*   wout_bf = (u16*)(ws + 17170432);      //    131,072 B
  u16*   biasT   = (u16*)(ws + 17301504);      //  1,048,576 B  bf16 [h][m][n], pre-scaled 1/ln2
  u16*   qkvb    = (u16*)(ws + 18350080);      // 50,331,648 B
  u16*   Ob      = (u16*)(ws + 68681728);      // 16,777,216 B  (total 85,458,944 B)

  k_cvt<<<4096, 256, 0, stream>>>(msa, msa_bf, 8388608/4);
  k_cvt2<<<256, 256, 0, stream>>>(Wqkv, wqkv_bf, Wout, wout_bf);
  k_pair_bias<<<4096, 256, 0, stream>>>(pair, mask, Wpb, bpb, biasT);
  k_qkv<<<dim3(6,256), 256, 0, stream>>>(msa_bf, wqkv_bf, bqkv, qkvb);
  k_attn<<<dim3(8,128,2), 256, 0, stream>>>(qkvb, biasT, Ob);
  k_out_ln<<<512, 256, 0, stream>>>(Ob, wout_bf, bout, msa, gamma, beta, out);
}